// Round 3
// baseline (300.211 us; speedup 1.0000x reference)
//
#include <hip/hip_runtime.h>

// Problem constants: x [32,64,64,64] f32, embed [64,512] f32.
#define N_VEC 131072   // 32*64*64 vectors
#define D 64           // embedding dim
#define K 512          // number of codes
#define QW 16          // queries per wave
#define BLK 512        // threads per block (8 waves)
#define QB (8 * QW)    // 128 queries per block
#define NBLK (N_VEC / QB)  // 1024 blocks

// ---------------------------------------------------------------------------
// Kernel 0: per-code squared norms (fma chain over d ascending — same order
// as rounds 1/2 so downstream score numerics are bit-identical).
// ---------------------------------------------------------------------------
__global__ __launch_bounds__(64) void vq_norm_kernel(
    const float* __restrict__ embed, float* __restrict__ nrm)
{
  const int k = blockIdx.x * 64 + threadIdx.x;  // grid 8 x 64
  float s = 0.f;
#pragma unroll
  for (int d = 0; d < D; ++d) { const float e = embed[d * K + k]; s = fmaf(e, e, s); }
  nrm[k] = s;
}

// ---------------------------------------------------------------------------
// Kernel A (fused): nearest-code search + gather q + diff partials.
// Lane = code (2 codes/lane per 128-code group, 4 groups). e tile staged in
// LDS [d][128] (b32, 2 lanes/bank = free). x read at wave-uniform addresses
// straight from global (scalar path; no LDS, no per-lane address math).
// Per lane: 2 codes x 16 queries = 32 fp32 accumulators.
// Epilogue: cross-lane argmin (np first-min semantics), then lane=dim gather
// of q from the L2-hot codebook + (q-x)^2 block partial.
// ---------------------------------------------------------------------------
__global__ __launch_bounds__(BLK) void vq_argmin_kernel(
    const float* __restrict__ x, const float* __restrict__ embed,
    const float* __restrict__ nrm, float* __restrict__ q,
    float* __restrict__ idf, float* __restrict__ partial)
{
  __shared__ float e_lds[D * 128];   // 32 KB: code-group tile [d][c]
  __shared__ float sred[8];
  const int tid  = threadIdx.x;
  const int lane = tid & 63;
  const int wv   = tid >> 6;         // 0..7
  const int qbase = __builtin_amdgcn_readfirstlane(blockIdx.x * QB + wv * QW);
  const float* __restrict__ xw = x + (size_t)qbase * D;  // wave-uniform base

  float best[QW];
  int bidx[QW];
#pragma unroll
  for (int i = 0; i < QW; ++i) { best[i] = 3.4e38f; bidx[i] = 0; }

#pragma unroll 1   // keep group loop rolled
  for (int g = 0; g < 4; ++g) {
    const float nr0 = nrm[g * 128 + lane];
    const float nr1 = nrm[g * 128 + 64 + lane];

    __syncthreads();   // previous group's compute done before overwrite
#pragma unroll
    for (int j = 0; j < 4; ++j) {       // stage e tile: 8192 floats / 512 thr
      const int f4 = tid + j * BLK;
      const int d = f4 >> 5;            // 32 float4 per 128-code row
      const int c = (f4 & 31) << 2;
      *reinterpret_cast<float4*>(&e_lds[d * 128 + c]) =
          *reinterpret_cast<const float4*>(&embed[d * K + g * 128 + c]);
    }
    __syncthreads();

    float acc0[QW], acc1[QW];
#pragma unroll
    for (int i = 0; i < QW; ++i) { acc0[i] = 0.f; acc1[i] = 0.f; }

#pragma unroll 4
    for (int ch = 0; ch < 16; ++ch) {   // 4 dims per chunk
      const int d0 = ch * 4;
      const float e00 = e_lds[(d0 + 0) * 128 + lane];
      const float e01 = e_lds[(d0 + 0) * 128 + 64 + lane];
      const float e10 = e_lds[(d0 + 1) * 128 + lane];
      const float e11 = e_lds[(d0 + 1) * 128 + 64 + lane];
      const float e20 = e_lds[(d0 + 2) * 128 + lane];
      const float e21 = e_lds[(d0 + 2) * 128 + 64 + lane];
      const float e30 = e_lds[(d0 + 3) * 128 + lane];
      const float e31 = e_lds[(d0 + 3) * 128 + 64 + lane];
#pragma unroll
      for (int i = 0; i < QW; ++i) {
        const float4 xv = *reinterpret_cast<const float4*>(xw + i * D + d0);
        acc0[i] = fmaf(xv.x, e00, acc0[i]);
        acc0[i] = fmaf(xv.y, e10, acc0[i]);
        acc0[i] = fmaf(xv.z, e20, acc0[i]);
        acc0[i] = fmaf(xv.w, e30, acc0[i]);
        acc1[i] = fmaf(xv.x, e01, acc1[i]);
        acc1[i] = fmaf(xv.y, e11, acc1[i]);
        acc1[i] = fmaf(xv.z, e21, acc1[i]);
        acc1[i] = fmaf(xv.w, e31, acc1[i]);
      }
    }

    // score = ||e||^2 - 2 x.e; strict < keeps the first (lowest-index) min;
    // per-lane visit order ascending in k — identical to rounds 1/2.
    const int k0 = g * 128 + lane;
#pragma unroll
    for (int i = 0; i < QW; ++i) {
      const float s0 = fmaf(-2.f, acc0[i], nr0);
      if (s0 < best[i]) { best[i] = s0; bidx[i] = k0; }
      const float s1 = fmaf(-2.f, acc1[i], nr1);
      if (s1 < best[i]) { best[i] = s1; bidx[i] = k0 + 64; }
    }
  }

  // Epilogue: per-query cross-lane argmin, id write, fused gather + diff.
  float dacc = 0.f;   // lane = dim: per-dim squared-diff accumulated over QW
#pragma unroll
  for (int i = 0; i < QW; ++i) {
    float s = best[i];
    int b = bidx[i];
#pragma unroll
    for (int off = 32; off > 0; off >>= 1) {
      const float s2 = __shfl_down(s, off, 64);
      const int   b2 = __shfl_down(b, off, 64);
      if (s2 < s || (s2 == s && b2 < b)) { s = s2; b = b2; }
    }
    const int id = __shfl(b, 0, 64);       // broadcast winner to all lanes
    if (lane == 0) idf[qbase + i] = (float)b;
    const float qv = embed[lane * K + id]; // L2-hot 128 KB codebook gather
    const float xv = xw[(size_t)i * D + lane];
    q[(size_t)(qbase + i) * D + lane] = qv;
    const float dv = qv - xv;
    dacc = fmaf(dv, dv, dacc);
  }
  // Deterministic block reduction of diff partials.
  dacc += __shfl_down(dacc, 32, 64);
  dacc += __shfl_down(dacc, 16, 64);
  dacc += __shfl_down(dacc, 8, 64);
  dacc += __shfl_down(dacc, 4, 64);
  dacc += __shfl_down(dacc, 2, 64);
  dacc += __shfl_down(dacc, 1, 64);
  if (lane == 0) sred[wv] = dacc;
  __syncthreads();
  if (tid == 0) {
    float t = 0.f;
#pragma unroll
    for (int w = 0; w < 8; ++w) t += sred[w];
    partial[blockIdx.x] = t;
  }
}

// ---------------------------------------------------------------------------
// Kernel C: sum the NBLK partials (fixed order) -> mean -> d_out scalar.
// ---------------------------------------------------------------------------
__global__ __launch_bounds__(256) void vq_finalize_kernel(
    const float* __restrict__ partial, float* __restrict__ out)
{
  float acc = 0.f;
  for (int i = threadIdx.x; i < NBLK; i += 256) acc += partial[i];
  acc += __shfl_down(acc, 32, 64);
  acc += __shfl_down(acc, 16, 64);
  acc += __shfl_down(acc, 8, 64);
  acc += __shfl_down(acc, 4, 64);
  acc += __shfl_down(acc, 2, 64);
  acc += __shfl_down(acc, 1, 64);
  __shared__ float sred[4];
  if ((threadIdx.x & 63) == 0) sred[threadIdx.x >> 6] = acc;
  __syncthreads();
  if (threadIdx.x == 0)
    out[0] = ((sred[0] + sred[1]) + (sred[2] + sred[3])) * (1.0f / (float)(N_VEC * D));
}

extern "C" void kernel_launch(void* const* d_in, const int* in_sizes, int n_in,
                              void* d_out, int out_size, void* d_ws, size_t ws_size,
                              hipStream_t stream) {
  const float* x = (const float*)d_in[0];
  const float* embed = (const float*)d_in[1];
  float* out = (float*)d_out;
  float* q = out;                      // [0, 8388608): q_st
  float* diff = out + 8388608;         // [8388608]: commitment loss scalar
  float* idf = out + 8388609;          // [8388609, +131072): emd_id as float
  float* nrm = (float*)d_ws;           // [0, 512): code norms
  float* partial = (float*)d_ws + 512; // NBLK partial sums

  vq_norm_kernel<<<8, 64, 0, stream>>>(embed, nrm);
  vq_argmin_kernel<<<NBLK, BLK, 0, stream>>>(x, embed, nrm, q, idf, partial);
  vq_finalize_kernel<<<1, 256, 0, stream>>>(partial, diff);
}